// Round 1
// baseline (1336.993 us; speedup 1.0000x reference)
//
#include <hip/hip_runtime.h>
#include <hip/hip_bf16.h>

#define SEQ 256
#define BATCH 16
#define MROWS 4096      // SEQ*BATCH
#define EMB 64
#define HID 32
#define G3 96           // 3*HID
#define KDIM 64         // 2*HID
#define VOCAB 50257
#define VPAD 50304      // VOCAB rounded up to multiple of 128
#define NCHUNK (VPAD/128)   // 393

using short8 = __attribute__((ext_vector_type(8))) short;
using float4v = __attribute__((ext_vector_type(4))) float;

__device__ __forceinline__ short f2bf(float x) {
    unsigned u = __float_as_uint(x);
    u = (u + 0x7fffu + ((u >> 16) & 1u)) >> 16;   // RNE
    return (short)u;
}

// ---------------------------------------------------------------- kernel 1
// x = embed[idx]; gx = x @ W_ih + b_ih for both directions.
__global__ __launch_bounds__(128) void k_embed_gx(
    const int* __restrict__ idx, const float* __restrict__ embed,
    const float* __restrict__ Wl, const float* __restrict__ bl,
    const float* __restrict__ Wr, const float* __restrict__ br,
    float* __restrict__ gxl, float* __restrict__ gxr) {
  int row = blockIdx.x;                 // s*BATCH + b
  int t = threadIdx.x;
  __shared__ float x[EMB];
  if (t < EMB) x[t] = embed[(size_t)idx[row] * EMB + t];
  __syncthreads();
  if (t < G3) {
    float al = bl[t], ar = br[t];
    #pragma unroll
    for (int e = 0; e < EMB; ++e) {
      float xe = x[e];
      al = fmaf(xe, Wl[e*G3 + t], al);
      ar = fmaf(xe, Wr[e*G3 + t], ar);
    }
    gxl[row*G3 + t] = al;
    gxr[row*G3 + t] = ar;
  }
}

// ---------------------------------------------------------------- kernel T
// Wt[v][k] = bf16(rnn_out[k][v]), zero-padded to VPAD rows.
__global__ __launch_bounds__(256) void k_transpose(
    const float* __restrict__ W, short* __restrict__ Wt) {
  __shared__ float tile[64][65];
  int v0 = blockIdx.x * 64;
  int t = threadIdx.x;
  #pragma unroll
  for (int i = 0; i < 16; ++i) {
    int e = i*256 + t;                  // 0..4095
    int k = e >> 6, v = e & 63;
    tile[k][v] = (v0 + v < VOCAB) ? W[(size_t)k*VOCAB + v0 + v] : 0.f;
  }
  __syncthreads();
  #pragma unroll
  for (int i = 0; i < 16; ++i) {
    int e = i*256 + t;
    int v = e >> 6, k = e & 63;
    Wt[(size_t)(v0 + v)*KDIM + k] = f2bf(tile[k][v]);
  }
}

// ---------------------------------------------------------------- kernel 2
// 32 independent chains (dir, b); one wave per chain; h lives in LDS.
// Single-wave block: DS ops are in-order, no __syncthreads in the loop
// (a barrier would force vmcnt(0) drain of the hbuf stores every step).
__global__ __launch_bounds__(64) void k_gru(
    const float* __restrict__ gxl, const float* __restrict__ gxr,
    const float* __restrict__ Wlhh, const float* __restrict__ blhh,
    const float* __restrict__ Wrhh, const float* __restrict__ brhh,
    float* __restrict__ hbuf) {
  int chain = blockIdx.x;
  int dir = chain >> 4;
  int b = chain & 15;
  const float* gx  = dir ? gxr  : gxl;
  const float* Whh = dir ? Wrhh : Wlhh;
  const float* bhh = dir ? brhh : blhh;
  int l = threadIdx.x;
  int jA = l;                 // lanes 0..31 -> r-gate col, 32..63 -> z-gate col
  int jB = 64 + (l & 31);     // n-gate col (meaningful for lanes < 32)
  float wA[HID], wB[HID];
  #pragma unroll
  for (int i = 0; i < HID; ++i) { wA[i] = Whh[i*G3 + jA]; wB[i] = Whh[i*G3 + jB]; }
  float bA = bhh[jA], bB = bhh[jB];
  __shared__ __align__(16) float hsh[HID];
  if (l < HID) hsh[l] = 0.f;
  int s0 = dir ? (SEQ-1) : 0;
  float gA = gx[(s0*BATCH + b)*G3 + jA];
  float gB = gx[(s0*BATCH + b)*G3 + jB];
  for (int t = 0; t < SEQ; ++t) {
    int s = dir ? (SEQ-1 - t) : t;
    int currow = s*BATCH + b;
    float gAn = 0.f, gBn = 0.f;
    if (t + 1 < SEQ) {                  // prefetch next step's gx
      int sn = dir ? (SEQ-2 - t) : (t+1);
      gAn = gx[(sn*BATCH + b)*G3 + jA];
      gBn = gx[(sn*BATCH + b)*G3 + jB];
    }
    float hv[HID];
    #pragma unroll
    for (int i = 0; i < 8; ++i) {       // 8x ds_read_b128 broadcast
      float4v h4 = ((const float4v*)hsh)[i];
      hv[4*i+0]=h4[0]; hv[4*i+1]=h4[1]; hv[4*i+2]=h4[2]; hv[4*i+3]=h4[3];
    }
    float hold = hsh[l & 31];
    float accA = bA, accB = bB;
    #pragma unroll
    for (int i = 0; i < HID; ++i) {
      accA = fmaf(hv[i], wA[i], accA);
      accB = fmaf(hv[i], wB[i], accB);
    }
    float preA = gA + accA;
    float sig = 1.f / (1.f + __expf(-preA));   // r (l<32) or z (l>=32)
    float n = tanhf(gB + sig * accB);          // valid for l<32
    float z = __shfl(sig, 32 + (l & 31));
    float hnew = (1.f - z) * n + z * hold;
    if (l < HID) {
      hsh[l] = hnew;
      hbuf[currow*KDIM + dir*HID + l] = hnew;
    }
    gA = gAn; gB = gBn;
  }
}

// ---------------------------------------------------------------- kernel 3
// Pass 1: rowsum[row] += sum_v exp(h.W_v + bias_v)   (no max needed: |logit|<=65)
__global__ __launch_bounds__(256) void k_lse(
    const float* __restrict__ hbuf, const short* __restrict__ Wt,
    const float* __restrict__ bias, float* __restrict__ rowsum) {
  int nb = blockIdx.x, mb = blockIdx.y, Nb = gridDim.x;
  int tid = threadIdx.x;
  int lane = tid & 63, wave = tid >> 6;
  int l15 = lane & 15, quad = lane >> 4;
  int m0 = mb*128 + wave*32;
  short8 afr[2][2];
  #pragma unroll
  for (int mt = 0; mt < 2; ++mt)
    #pragma unroll
    for (int kc = 0; kc < 2; ++kc) {
      const float* ap = hbuf + (m0 + mt*16 + l15)*KDIM + kc*32 + quad*8;
      float4v a0 = *(const float4v*)ap;
      float4v a1 = *(const float4v*)(ap + 4);
      short8 f;
      f[0]=f2bf(a0[0]); f[1]=f2bf(a0[1]); f[2]=f2bf(a0[2]); f[3]=f2bf(a0[3]);
      f[4]=f2bf(a1[0]); f[5]=f2bf(a1[1]); f[6]=f2bf(a1[2]); f[7]=f2bf(a1[3]);
      afr[mt][kc] = f;
    }
  float part[2][4] = {};
  for (int c = nb; c < NCHUNK; c += Nb) {
    int v0 = c*128;
    float4v acc[2][8];
    #pragma unroll
    for (int mt = 0; mt < 2; ++mt)
      #pragma unroll
      for (int nt = 0; nt < 8; ++nt)
        acc[mt][nt] = (float4v){0.f,0.f,0.f,0.f};
    #pragma unroll
    for (int kc = 0; kc < 2; ++kc)
      #pragma unroll
      for (int nt = 0; nt < 8; ++nt) {
        short8 bf = *(const short8*)(Wt + (size_t)(v0 + nt*16 + l15)*KDIM + kc*32 + quad*8);
        acc[0][nt] = __builtin_amdgcn_mfma_f32_16x16x32_bf16(afr[0][kc], bf, acc[0][nt], 0,0,0);
        acc[1][nt] = __builtin_amdgcn_mfma_f32_16x16x32_bf16(afr[1][kc], bf, acc[1][nt], 0,0,0);
      }
    #pragma unroll
    for (int nt = 0; nt < 8; ++nt) {
      int col = v0 + nt*16 + l15;
      bool ok = col < VOCAB;
      float bv = ok ? bias[col] : 0.f;
      #pragma unroll
      for (int mt = 0; mt < 2; ++mt)
        #pragma unroll
        for (int r = 0; r < 4; ++r) {
          float e = __expf(acc[mt][nt][r] + bv);
          part[mt][r] += ok ? e : 0.f;
        }
    }
  }
  #pragma unroll
  for (int mt = 0; mt < 2; ++mt)
    #pragma unroll
    for (int r = 0; r < 4; ++r) {
      float v = part[mt][r];
      v += __shfl_xor(v, 1);
      v += __shfl_xor(v, 2);
      v += __shfl_xor(v, 4);
      v += __shfl_xor(v, 8);
      if (l15 == 0) atomicAdd(&rowsum[m0 + mt*16 + quad*4 + r], v);
    }
}

// ---------------------------------------------------------------- kernel 4
// Pass 2: recompute logits, write out = logit + bias - log(rowsum[row]).
__global__ __launch_bounds__(256) void k_out(
    const float* __restrict__ hbuf, const short* __restrict__ Wt,
    const float* __restrict__ bias, const float* __restrict__ rowsum,
    float* __restrict__ out) {
  int nb = blockIdx.x, mb = blockIdx.y, Nb = gridDim.x;
  int tid = threadIdx.x;
  int lane = tid & 63, wave = tid >> 6;
  int l15 = lane & 15, quad = lane >> 4;
  int m0 = mb*128 + wave*32;
  short8 afr[2][2];
  #pragma unroll
  for (int mt = 0; mt < 2; ++mt)
    #pragma unroll
    for (int kc = 0; kc < 2; ++kc) {
      const float* ap = hbuf + (m0 + mt*16 + l15)*KDIM + kc*32 + quad*8;
      float4v a0 = *(const float4v*)ap;
      float4v a1 = *(const float4v*)(ap + 4);
      short8 f;
      f[0]=f2bf(a0[0]); f[1]=f2bf(a0[1]); f[2]=f2bf(a0[2]); f[3]=f2bf(a0[3]);
      f[4]=f2bf(a1[0]); f[5]=f2bf(a1[1]); f[6]=f2bf(a1[2]); f[7]=f2bf(a1[3]);
      afr[mt][kc] = f;
    }
  float lse[2][4];
  #pragma unroll
  for (int mt = 0; mt < 2; ++mt)
    #pragma unroll
    for (int r = 0; r < 4; ++r)
      lse[mt][r] = logf(rowsum[m0 + mt*16 + quad*4 + r]);
  for (int c = nb; c < NCHUNK; c += Nb) {
    int v0 = c*128;
    float4v acc[2][8];
    #pragma unroll
    for (int mt = 0; mt < 2; ++mt)
      #pragma unroll
      for (int nt = 0; nt < 8; ++nt)
        acc[mt][nt] = (float4v){0.f,0.f,0.f,0.f};
    #pragma unroll
    for (int kc = 0; kc < 2; ++kc)
      #pragma unroll
      for (int nt = 0; nt < 8; ++nt) {
        short8 bf = *(const short8*)(Wt + (size_t)(v0 + nt*16 + l15)*KDIM + kc*32 + quad*8);
        acc[0][nt] = __builtin_amdgcn_mfma_f32_16x16x32_bf16(afr[0][kc], bf, acc[0][nt], 0,0,0);
        acc[1][nt] = __builtin_amdgcn_mfma_f32_16x16x32_bf16(afr[1][kc], bf, acc[1][nt], 0,0,0);
      }
    #pragma unroll
    for (int nt = 0; nt < 8; ++nt) {
      int col = v0 + nt*16 + l15;
      if (col < VOCAB) {
        float bv = bias[col];
        #pragma unroll
        for (int mt = 0; mt < 2; ++mt) {
          long base = (long)(m0 + mt*16 + quad*4) * VOCAB + col;
          #pragma unroll
          for (int r = 0; r < 4; ++r)
            out[base + (long)r*VOCAB] = acc[mt][nt][r] + bv - lse[mt][r];
        }
      }
    }
  }
}

// ---------------------------------------------------------------- launch
extern "C" void kernel_launch(void* const* d_in, const int* in_sizes, int n_in,
                              void* d_out, int out_size, void* d_ws, size_t ws_size,
                              hipStream_t stream) {
  const int*   idx   = (const int*)d_in[0];
  const float* embed = (const float*)d_in[1];
  const float* W     = (const float*)d_in[2];
  const float* bias  = (const float*)d_in[3];
  const float* Wl_ih = (const float*)d_in[4];
  const float* Wl_hh = (const float*)d_in[5];
  const float* bl_ih = (const float*)d_in[6];
  const float* bl_hh = (const float*)d_in[7];
  const float* Wr_ih = (const float*)d_in[8];
  const float* Wr_hh = (const float*)d_in[9];
  const float* br_ih = (const float*)d_in[10];
  const float* br_hh = (const float*)d_in[11];
  float* out = (float*)d_out;
  char* ws = (char*)d_ws;
  // workspace layout (bytes): gxl 1.5M | gxr 1.5M | hbuf 1M | rowsum 16K | Wt 6.4M
  float* gxl    = (float*)(ws);
  float* gxr    = (float*)(ws + 1572864);
  float* hbuf   = (float*)(ws + 3145728);
  float* rowsum = (float*)(ws + 4194304);
  short* Wt     = (short*)(ws + 4210688);   // total ~10.2 MB

  hipMemsetAsync(rowsum, 0, MROWS*sizeof(float), stream);
  k_embed_gx<<<MROWS, 128, 0, stream>>>(idx, embed, Wl_ih, bl_ih, Wr_ih, br_ih, gxl, gxr);
  k_transpose<<<VPAD/64, 256, 0, stream>>>(W, Wt);
  k_gru<<<32, 64, 0, stream>>>(gxl, gxr, Wl_hh, bl_hh, Wr_hh, br_hh, hbuf);
  k_lse<<<dim3(32, 32), 256, 0, stream>>>(hbuf, Wt, bias, rowsum);
  k_out<<<dim3(64, 32), 256, 0, stream>>>(hbuf, Wt, bias, rowsum, out);
}

// Round 2
// 1270.259 us; speedup vs baseline: 1.0525x; 1.0525x over previous
//
#include <hip/hip_runtime.h>
#include <hip/hip_bf16.h>

#define SEQ 256
#define BATCH 16
#define MROWS 4096      // SEQ*BATCH
#define EMB 64
#define HID 32
#define G3 96           // 3*HID
#define KDIM 64         // 2*HID
#define VOCAB 50257
#define VPAD 50304      // VOCAB rounded up to multiple of 128
#define NCHUNK (VPAD/128)   // 393
#define NTBLK (VPAD/64)     // 786 transpose blocks

using short8 = __attribute__((ext_vector_type(8))) short;
using float4v = __attribute__((ext_vector_type(4))) float;

__device__ __forceinline__ short f2bf(float x) {
    unsigned u = __float_as_uint(x);
    u = (u + 0x7fffu + ((u >> 16) & 1u)) >> 16;   // RNE
    return (short)u;
}

__device__ __forceinline__ void store16_u(float* p, float4v v) {
    // out row pitch is VOCAB (odd) -> 16B stores are only 4B-aligned.
    __builtin_memcpy((void*)p, &v, 16);
}

// ---------------------------------------------------------------- prep
// blocks [0, NTBLK):       Wt[v][k] = bf16(rnn_out[k][v]) + biasp fill
// blocks [NTBLK, +2048):   x = embed[idx]; gx = x @ W_ih + b_ih (2 rows/block)
__global__ __launch_bounds__(256) void k_prep(
    const int* __restrict__ idx, const float* __restrict__ embed,
    const float* __restrict__ Wl, const float* __restrict__ bl,
    const float* __restrict__ Wr, const float* __restrict__ br,
    float* __restrict__ gxl, float* __restrict__ gxr,
    const float* __restrict__ W, short* __restrict__ Wt,
    const float* __restrict__ bias, float* __restrict__ biasp) {
  __shared__ float smem[64*65];
  int t = threadIdx.x;
  int blk = blockIdx.x;
  if (blk < NTBLK) {
    int v0 = blk * 64;
    if (t < 64) {
      int v = v0 + t;
      biasp[v] = (v < VOCAB) ? bias[v] : -1e30f;   // pad: exp() -> 0
    }
    #pragma unroll
    for (int i = 0; i < 16; ++i) {
      int e = i*256 + t;                  // 0..4095
      int k = e >> 6, v = e & 63;
      smem[k*65 + v] = (v0 + v < VOCAB) ? W[(size_t)k*VOCAB + v0 + v] : 0.f;
    }
    __syncthreads();
    #pragma unroll
    for (int i = 0; i < 16; ++i) {
      int e = i*256 + t;
      int v = e >> 6, k = e & 63;
      Wt[(size_t)(v0 + v)*KDIM + k] = f2bf(smem[k*65 + v]);
    }
  } else {
    int row2 = blk - NTBLK;               // 0..2047
    int half = t >> 7, tt = t & 127;
    int row = row2*2 + half;
    float* x = smem + half*EMB;
    if (tt < EMB) x[tt] = embed[(size_t)idx[row] * EMB + tt];
    __syncthreads();
    if (tt < G3) {
      float al = bl[tt], ar = br[tt];
      #pragma unroll
      for (int e = 0; e < EMB; ++e) {
        float xe = x[e];
        al = fmaf(xe, Wl[e*G3 + tt], al);
        ar = fmaf(xe, Wr[e*G3 + tt], ar);
      }
      gxl[row*G3 + tt] = al;
      gxr[row*G3 + tt] = ar;
    }
  }
}

// ---------------------------------------------------------------- kernel 2
// 32 independent chains (dir, b); one wave per chain; h lives in LDS.
// Single-wave block: DS ops are in-order, no __syncthreads in the loop.
// Acc chains split 4-way: dep chain 128cy -> ~40cy per step.
__global__ __launch_bounds__(64) void k_gru(
    const float* __restrict__ gxl, const float* __restrict__ gxr,
    const float* __restrict__ Wlhh, const float* __restrict__ blhh,
    const float* __restrict__ Wrhh, const float* __restrict__ brhh,
    float* __restrict__ hbuf) {
  int chain = blockIdx.x;
  int dir = chain >> 4;
  int b = chain & 15;
  const float* gx  = dir ? gxr  : gxl;
  const float* Whh = dir ? Wrhh : Wlhh;
  const float* bhh = dir ? brhh : blhh;
  int l = threadIdx.x;
  int jA = l;                 // lanes 0..31 -> r-gate col, 32..63 -> z-gate col
  int jB = 64 + (l & 31);     // n-gate col (meaningful for lanes < 32)
  float wA[HID], wB[HID];
  #pragma unroll
  for (int i = 0; i < HID; ++i) { wA[i] = Whh[i*G3 + jA]; wB[i] = Whh[i*G3 + jB]; }
  float bA = bhh[jA], bB = bhh[jB];
  __shared__ __align__(16) float hsh[HID];
  if (l < HID) hsh[l] = 0.f;
  int s0 = dir ? (SEQ-1) : 0;
  float gA = gx[(s0*BATCH + b)*G3 + jA];
  float gB = gx[(s0*BATCH + b)*G3 + jB];
  for (int t = 0; t < SEQ; ++t) {
    int s = dir ? (SEQ-1 - t) : t;
    int currow = s*BATCH + b;
    float gAn = 0.f, gBn = 0.f;
    if (t + 1 < SEQ) {                  // prefetch next step's gx
      int sn = dir ? (SEQ-2 - t) : (t+1);
      gAn = gx[(sn*BATCH + b)*G3 + jA];
      gBn = gx[(sn*BATCH + b)*G3 + jB];
    }
    float hv[HID];
    #pragma unroll
    for (int i = 0; i < 8; ++i) {       // 8x ds_read_b128 broadcast
      float4v h4 = ((const float4v*)hsh)[i];
      hv[4*i+0]=h4[0]; hv[4*i+1]=h4[1]; hv[4*i+2]=h4[2]; hv[4*i+3]=h4[3];
    }
    float hold = hsh[l & 31];
    float aA0 = bA, aA1 = 0.f, aA2 = 0.f, aA3 = 0.f;
    float aB0 = bB, aB1 = 0.f, aB2 = 0.f, aB3 = 0.f;
    #pragma unroll
    for (int i = 0; i < 8; ++i) {
      aA0 = fmaf(hv[4*i+0], wA[4*i+0], aA0);
      aA1 = fmaf(hv[4*i+1], wA[4*i+1], aA1);
      aA2 = fmaf(hv[4*i+2], wA[4*i+2], aA2);
      aA3 = fmaf(hv[4*i+3], wA[4*i+3], aA3);
      aB0 = fmaf(hv[4*i+0], wB[4*i+0], aB0);
      aB1 = fmaf(hv[4*i+1], wB[4*i+1], aB1);
      aB2 = fmaf(hv[4*i+2], wB[4*i+2], aB2);
      aB3 = fmaf(hv[4*i+3], wB[4*i+3], aB3);
    }
    float accA = (aA0 + aA1) + (aA2 + aA3);
    float accB = (aB0 + aB1) + (aB2 + aB3);
    float preA = gA + accA;
    float sig = __builtin_amdgcn_rcpf(1.f + __expf(-preA));  // r (l<32) / z (l>=32)
    float y = gB + sig * accB;
    float e2 = __expf(2.f * y);                              // tanh via exp+rcp
    float n = 1.f - 2.f * __builtin_amdgcn_rcpf(e2 + 1.f);
    float z = __shfl(sig, 32 + (l & 31));
    float hnew = (1.f - z) * n + z * hold;
    if (l < HID) {
      hsh[l] = hnew;
      hbuf[currow*KDIM + dir*HID + l] = hnew;
    }
    gA = gAn; gB = gBn;
  }
}

// ---------------------------------------------------------------- kernel 3
// Pass 1: rowsum[m] += sum_v exp(h.W_v + bias_v).  MFMA operands swapped
// (A = W-frag, B = h-frag): lane's 4 acc values = 4 consecutive vocab of ONE
// row m = m0+mt*16+l15.  Pad vocab masked via biasp = -1e30.
__global__ __launch_bounds__(256) void k_lse(
    const float* __restrict__ hbuf, const short* __restrict__ Wt,
    const float* __restrict__ biasp, float* __restrict__ rowsum) {
  int nb = blockIdx.x, mb = blockIdx.y, Nb = gridDim.x;
  int tid = threadIdx.x;
  int lane = tid & 63, wave = tid >> 6;
  int l15 = lane & 15, quad = lane >> 4;
  int m0 = mb*128 + wave*32;
  short8 afr[2][2];
  #pragma unroll
  for (int mt = 0; mt < 2; ++mt)
    #pragma unroll
    for (int kc = 0; kc < 2; ++kc) {
      const float* ap = hbuf + (m0 + mt*16 + l15)*KDIM + kc*32 + quad*8;
      float4v a0 = *(const float4v*)ap;
      float4v a1 = *(const float4v*)(ap + 4);
      short8 f;
      f[0]=f2bf(a0[0]); f[1]=f2bf(a0[1]); f[2]=f2bf(a0[2]); f[3]=f2bf(a0[3]);
      f[4]=f2bf(a1[0]); f[5]=f2bf(a1[1]); f[6]=f2bf(a1[2]); f[7]=f2bf(a1[3]);
      afr[mt][kc] = f;
    }
  float part[2] = {0.f, 0.f};
  for (int c = nb; c < NCHUNK; c += Nb) {
    int v0 = c*128;
    float4v acc[2][8];
    #pragma unroll
    for (int mt = 0; mt < 2; ++mt)
      #pragma unroll
      for (int nt = 0; nt < 8; ++nt)
        acc[mt][nt] = (float4v){0.f,0.f,0.f,0.f};
    #pragma unroll
    for (int kc = 0; kc < 2; ++kc)
      #pragma unroll
      for (int nt = 0; nt < 8; ++nt) {
        short8 wf = *(const short8*)(Wt + (size_t)(v0 + nt*16 + l15)*KDIM + kc*32 + quad*8);
        acc[0][nt] = __builtin_amdgcn_mfma_f32_16x16x32_bf16(wf, afr[0][kc], acc[0][nt], 0,0,0);
        acc[1][nt] = __builtin_amdgcn_mfma_f32_16x16x32_bf16(wf, afr[1][kc], acc[1][nt], 0,0,0);
      }
    #pragma unroll
    for (int nt = 0; nt < 8; ++nt) {
      int vb = v0 + nt*16 + quad*4;
      float4v bv = *(const float4v*)(biasp + vb);
      #pragma unroll
      for (int mt = 0; mt < 2; ++mt)
        #pragma unroll
        for (int r = 0; r < 4; ++r)
          part[mt] += __expf(acc[mt][nt][r] + bv[r]);
    }
  }
  #pragma unroll
  for (int mt = 0; mt < 2; ++mt) {
    float v = part[mt];
    v += __shfl_xor(v, 16);
    v += __shfl_xor(v, 32);
    if (lane < 16) atomicAdd(&rowsum[m0 + mt*16 + l15], v);
  }
}

// ---------------------------------------------------------------- kernel 4
// Pass 2: recompute logits (swapped operands), write float4 per lane:
// out[m][vb..vb+3] = logit + bias - log(rowsum[m]).
__global__ __launch_bounds__(256) void k_out(
    const float* __restrict__ hbuf, const short* __restrict__ Wt,
    const float* __restrict__ biasp, const float* __restrict__ rowsum,
    float* __restrict__ out) {
  int nb = blockIdx.x, mb = blockIdx.y, Nb = gridDim.x;
  int tid = threadIdx.x;
  int lane = tid & 63, wave = tid >> 6;
  int l15 = lane & 15, quad = lane >> 4;
  int m0 = mb*128 + wave*32;
  short8 afr[2][2];
  #pragma unroll
  for (int mt = 0; mt < 2; ++mt)
    #pragma unroll
    for (int kc = 0; kc < 2; ++kc) {
      const float* ap = hbuf + (m0 + mt*16 + l15)*KDIM + kc*32 + quad*8;
      float4v a0 = *(const float4v*)ap;
      float4v a1 = *(const float4v*)(ap + 4);
      short8 f;
      f[0]=f2bf(a0[0]); f[1]=f2bf(a0[1]); f[2]=f2bf(a0[2]); f[3]=f2bf(a0[3]);
      f[4]=f2bf(a1[0]); f[5]=f2bf(a1[1]); f[6]=f2bf(a1[2]); f[7]=f2bf(a1[3]);
      afr[mt][kc] = f;
    }
  float lsev[2];
  #pragma unroll
  for (int mt = 0; mt < 2; ++mt)
    lsev[mt] = __logf(rowsum[m0 + mt*16 + l15]);
  for (int c = nb; c < NCHUNK; c += Nb) {
    int v0 = c*128;
    float4v acc[2][8];
    #pragma unroll
    for (int mt = 0; mt < 2; ++mt)
      #pragma unroll
      for (int nt = 0; nt < 8; ++nt)
        acc[mt][nt] = (float4v){0.f,0.f,0.f,0.f};
    #pragma unroll
    for (int kc = 0; kc < 2; ++kc)
      #pragma unroll
      for (int nt = 0; nt < 8; ++nt) {
        short8 wf = *(const short8*)(Wt + (size_t)(v0 + nt*16 + l15)*KDIM + kc*32 + quad*8);
        acc[0][nt] = __builtin_amdgcn_mfma_f32_16x16x32_bf16(wf, afr[0][kc], acc[0][nt], 0,0,0);
        acc[1][nt] = __builtin_amdgcn_mfma_f32_16x16x32_bf16(wf, afr[1][kc], acc[1][nt], 0,0,0);
      }
    if (v0 + 128 <= VOCAB) {            // fast path: all stores in-bounds
      #pragma unroll
      for (int nt = 0; nt < 8; ++nt) {
        int vb = v0 + nt*16 + quad*4;
        float4v bv = *(const float4v*)(biasp + vb);
        #pragma unroll
        for (int mt = 0; mt < 2; ++mt) {
          long m = m0 + mt*16 + l15;
          float4v o;
          #pragma unroll
          for (int r = 0; r < 4; ++r) o[r] = acc[mt][nt][r] + bv[r] - lsev[mt];
          store16_u(out + m*VOCAB + vb, o);
        }
      }
    } else {                            // tail chunk: masked scalar stores
      #pragma unroll
      for (int nt = 0; nt < 8; ++nt) {
        int vb = v0 + nt*16 + quad*4;
        float4v bv = *(const float4v*)(biasp + vb);
        #pragma unroll
        for (int mt = 0; mt < 2; ++mt) {
          long m = m0 + mt*16 + l15;
          #pragma unroll
          for (int r = 0; r < 4; ++r)
            if (vb + r < VOCAB)
              out[m*VOCAB + vb + r] = acc[mt][nt][r] + bv[r] - lsev[mt];
        }
      }
    }
  }
}

// ---------------------------------------------------------------- launch
extern "C" void kernel_launch(void* const* d_in, const int* in_sizes, int n_in,
                              void* d_out, int out_size, void* d_ws, size_t ws_size,
                              hipStream_t stream) {
  const int*   idx   = (const int*)d_in[0];
  const float* embed = (const float*)d_in[1];
  const float* W     = (const float*)d_in[2];
  const float* bias  = (const float*)d_in[3];
  const float* Wl_ih = (const float*)d_in[4];
  const float* Wl_hh = (const float*)d_in[5];
  const float* bl_ih = (const float*)d_in[6];
  const float* bl_hh = (const float*)d_in[7];
  const float* Wr_ih = (const float*)d_in[8];
  const float* Wr_hh = (const float*)d_in[9];
  const float* br_ih = (const float*)d_in[10];
  const float* br_hh = (const float*)d_in[11];
  float* out = (float*)d_out;
  char* ws = (char*)d_ws;
  // workspace (bytes): gxl 1.5M | gxr 1.5M | hbuf 1M | rowsum 16K | biasp 201K | Wt 6.4M
  float* gxl    = (float*)(ws);
  float* gxr    = (float*)(ws + 1572864);
  float* hbuf   = (float*)(ws + 3145728);
  float* rowsum = (float*)(ws + 4194304);
  float* biasp  = (float*)(ws + 4210688);
  short* Wt     = (short*)(ws + 4411904);   // total ~10.35 MB

  hipMemsetAsync(rowsum, 0, MROWS*sizeof(float), stream);
  k_prep<<<NTBLK + 2048, 256, 0, stream>>>(idx, embed, Wl_ih, bl_ih, Wr_ih, br_ih,
                                           gxl, gxr, W, Wt, bias, biasp);
  k_gru<<<32, 64, 0, stream>>>(gxl, gxr, Wl_hh, bl_hh, Wr_hh, br_hh, hbuf);
  k_lse<<<dim3(64, 32), 256, 0, stream>>>(hbuf, Wt, biasp, rowsum);
  k_out<<<dim3(64, 32), 256, 0, stream>>>(hbuf, Wt, biasp, rowsum, out);
}